// Round 1
// baseline (695.393 us; speedup 1.0000x reference)
//
#include <hip/hip_runtime.h>
#include <math.h>

// Problem constants (from reference)
#define HORIZON 20
#define NCLASS  36
constexpr float STEP = 2.0f;
constexpr float TWO_PI_OVER_C = 0.17453292519943295f; // 2*pi/36
constexpr float OBS_RADIUS = 1.0f;
// VEH_RADIUS = 2.0 -> compare d^2 < 4.0

struct Accum {
    double dist_sum;          // 0
    double osum;              // 8
    double vsum;              // 16
    unsigned long long nveh;  // 24
    unsigned long long ocnt;  // 32
    unsigned long long vcnt;  // 40
};

__global__ void init_accum(Accum* a) {
    if (threadIdx.x == 0) {
        a->dist_sum = 0.0; a->osum = 0.0; a->vsum = 0.0;
        a->nveh = 0ull; a->ocnt = 0ull; a->vcnt = 0ull;
    }
}

// Per-wave reduce (sum,count) then one atomic pair per wave.
__device__ __forceinline__ void wave_commit(float sum, unsigned cnt,
                                            double* dsum, unsigned long long* dcnt) {
    #pragma unroll
    for (int off = 32; off > 0; off >>= 1) {
        sum += __shfl_down(sum, off, 64);
        cnt += __shfl_down(cnt, off, 64);
    }
    if ((threadIdx.x & 63) == 0) {
        if (sum != 0.0f) atomicAdd(dsum, (double)sum);
        if (cnt != 0u)   atomicAdd(dcnt, (unsigned long long)cnt);
    }
}

// Kernel 1: per (node,h) class decode -> step vector (STEP*cos, STEP*sin)
// written into traj buffer (later cumsum'd in place).
__global__ void angles_kernel(const float* __restrict__ pred,
                              float2* __restrict__ traj, int total) {
    int idx = blockIdx.x * blockDim.x + threadIdx.x;
    if (idx >= total) return;
    const float4* p = (const float4*)(pred + (size_t)idx * NCLASS);
    float4 v[9];
    #pragma unroll
    for (int q = 0; q < 9; q++) v[q] = p[q];
    float best = -INFINITY; int bi = 0;
    #pragma unroll
    for (int q = 0; q < 9; q++) {
        float vals[4] = {v[q].x, v[q].y, v[q].z, v[q].w};
        #pragma unroll
        for (int k = 0; k < 4; k++) {
            int c = q * 4 + k;
            if (vals[k] > best) { best = vals[k]; bi = c; }  // strict > == first argmax
        }
    }
    float ang = (float)bi * TWO_PI_OVER_C * best;
    float s, c;
    sincosf(ang, &s, &c);
    traj[idx] = make_float2(STEP * c, STEP * s);
}

// Kernel 2: per-node sequential rollout (cumsum), vehicle masking, distance-loss partials.
__global__ void rollout_kernel(const float* __restrict__ X,
                               float2* __restrict__ traj,
                               Accum* acc, int n_nodes) {
    int n = blockIdx.x * blockDim.x + threadIdx.x;
    float dsum = 0.0f; unsigned vehc = 0;
    if (n < n_nodes) {
        const float* xr = X + (size_t)n * 5;
        float typ = xr[0];
        float px  = xr[1];
        float py  = xr[2];
        float tx  = xr[3];
        float ty  = xr[4];
        bool veh = (typ == 0.0f);
        float4* tp = (float4*)(traj + (size_t)n * HORIZON);
        float4 buf[10];
        #pragma unroll
        for (int q = 0; q < 10; q++) buf[q] = tp[q];
        float* f = (float*)buf;
        #pragma unroll
        for (int h = 0; h < HORIZON; h++) {
            px += f[2*h]; py += f[2*h+1];
            float ox = veh ? px : 0.0f;
            float oy = veh ? py : 0.0f;
            f[2*h] = ox; f[2*h+1] = oy;
            float dx = tx - ox, dy = ty - oy;
            dsum += veh ? sqrtf(fmaf(dy, dy, dx*dx)) : 0.0f;
        }
        #pragma unroll
        for (int q = 0; q < 10; q++) tp[q] = buf[q];
        vehc = veh ? 1u : 0u;
    }
    wave_commit(dsum, vehc, &acc->dist_sum, &acc->nveh);
}

// Kernel 3: obstacle edges. thr = X[src,3] + OBS_RADIUS can be negative -> must
// compare real distance, not squared.
__global__ void obstacle_kernel(const float* __restrict__ X,
                                const int* __restrict__ eo,
                                const float2* __restrict__ traj,
                                Accum* acc, int mo) {
    int e = blockIdx.x * blockDim.x + threadIdx.x;
    float osum = 0.0f; unsigned ocnt = 0;
    if (e < mo) {
        int src = eo[e];
        int dst = eo[mo + e];
        const float* xr = X + (size_t)src * 5;
        float fx = xr[1], fy = xr[2];
        float thr = xr[3] + OBS_RADIUS;
        const float4* tp = (const float4*)(traj + (size_t)dst * HORIZON);
        float4 buf[10];
        #pragma unroll
        for (int q = 0; q < 10; q++) buf[q] = tp[q];
        const float* f = (const float*)buf;
        #pragma unroll
        for (int h = 0; h < HORIZON; h++) {
            float dx = fx - f[2*h], dy = fy - f[2*h+1];
            float d2 = fmaf(dy, dy, dx*dx);
            float od = sqrtf(d2);
            bool near = od < thr;
            ocnt += near ? 1u : 0u;
            osum += near ? (1.0f / od) : 0.0f;
        }
    }
    wave_commit(osum, ocnt, &acc->osum, &acc->ocnt);
}

// Kernel 4: vehicle edges, HxH all-pairs. B-trajectory pinned in 40 VGPRs
// (inner loop fully unrolled so the register array stays in registers);
// A-trajectory streamed per outer step from cache. Branchless rsqrt select.
__global__ void vehicle_kernel(const int* __restrict__ ev,
                               const float2* __restrict__ traj,
                               Accum* acc, int mv) {
    int e = blockIdx.x * blockDim.x + threadIdx.x;
    float vsum = 0.0f; unsigned vcnt = 0;
    if (e < mv) {
        int a = ev[e];
        int b = ev[mv + e];
        const float4* pb = (const float4*)(traj + (size_t)b * HORIZON);
        float4 tb[10];
        #pragma unroll
        for (int q = 0; q < 10; q++) tb[q] = pb[q];
        const float* fb = (const float*)tb;
        const float2* pa = traj + (size_t)a * HORIZON;
        for (int i = 0; i < HORIZON; i++) {
            float2 av = pa[i];
            #pragma unroll
            for (int j = 0; j < HORIZON; j++) {
                float dx = av.x - fb[2*j];
                float dy = av.y - fb[2*j+1];
                float d2 = fmaf(dy, dy, dx*dx);
                bool near = d2 < 4.0f;   // vd < 2  <=>  d2 < 4
                vcnt += near ? 1u : 0u;
                vsum += near ? rsqrtf(d2) : 0.0f;  // 1/vd = rsqrt(d2)
            }
        }
    }
    wave_commit(vsum, vcnt, &acc->vsum, &acc->vcnt);
}

__global__ void finalize_kernel(const Accum* __restrict__ acc, float* __restrict__ out) {
    if (threadIdx.x == 0 && blockIdx.x == 0) {
        float dist = (acc->nveh > 0)
            ? (float)(acc->dist_sum / ((double)acc->nveh * (double)HORIZON)) : 0.0f;
        float obs = (acc->ocnt > 0) ? (float)(acc->osum / (double)acc->ocnt) : 0.0f;
        float veh = (acc->vcnt > 0) ? (float)(acc->vsum / (double)acc->vcnt) : 0.0f;
        out[0] = dist + obs + veh;  // total
        out[1] = dist;
        out[2] = obs;
        out[3] = veh;
    }
}

extern "C" void kernel_launch(void* const* d_in, const int* in_sizes, int n_in,
                              void* d_out, int out_size, void* d_ws, size_t ws_size,
                              hipStream_t stream) {
    const float* X    = (const float*)d_in[0];
    const float* pred = (const float*)d_in[1];
    const int*   ev   = (const int*)d_in[2];
    const int*   eo   = (const int*)d_in[3];
    int n_nodes = in_sizes[0] / 5;
    int mv = in_sizes[2] / 2;
    int mo = in_sizes[3] / 2;

    Accum* acc = (Accum*)d_ws;
    float2* traj = (float2*)((char*)d_ws + 64);   // N*H float2 = 16 MB
    float* out = (float*)d_out;

    hipLaunchKernelGGL(init_accum, dim3(1), dim3(64), 0, stream, acc);

    int total = n_nodes * HORIZON;
    hipLaunchKernelGGL(angles_kernel, dim3((total + 255) / 256), dim3(256), 0, stream,
                       pred, traj, total);
    hipLaunchKernelGGL(rollout_kernel, dim3((n_nodes + 255) / 256), dim3(256), 0, stream,
                       X, traj, acc, n_nodes);
    hipLaunchKernelGGL(obstacle_kernel, dim3((mo + 255) / 256), dim3(256), 0, stream,
                       X, eo, traj, acc, mo);
    hipLaunchKernelGGL(vehicle_kernel, dim3((mv + 255) / 256), dim3(256), 0, stream,
                       ev, traj, acc, mv);
    hipLaunchKernelGGL(finalize_kernel, dim3(1), dim3(64), 0, stream, acc, out);
}

// Round 2
// 487.075 us; speedup vs baseline: 1.4277x; 1.4277x over previous
//
#include <hip/hip_runtime.h>
#include <math.h>

#define HORIZON 20
#define NCLASS  36
constexpr float STEP = 2.0f;
constexpr float TWO_PI_OVER_C = 0.17453292519943295f; // 2*pi/36
constexpr float OBS_RADIUS = 1.0f;
// VEH_RADIUS = 2.0 -> compare d^2 < 4.0

// Per-block (sum,count) reduction -> non-atomic partial store.
// ALL threads of the block must call this (no early returns before it).
template <int BS>
__device__ __forceinline__ void block_commit(float sum, unsigned cnt,
                                             float* __restrict__ pOut,
                                             unsigned* __restrict__ cOut) {
    __shared__ float    ls[BS / 64];
    __shared__ unsigned lc[BS / 64];
    #pragma unroll
    for (int off = 32; off > 0; off >>= 1) {
        sum += __shfl_down(sum, off, 64);
        cnt += __shfl_down(cnt, off, 64);
    }
    int wid = threadIdx.x >> 6;
    if ((threadIdx.x & 63) == 0) { ls[wid] = sum; lc[wid] = cnt; }
    __syncthreads();
    if (threadIdx.x == 0) {
        float s = 0.0f; unsigned c = 0u;
        #pragma unroll
        for (int w = 0; w < BS / 64; w++) { s += ls[w]; c += lc[w]; }
        pOut[blockIdx.x] = s;
        cOut[blockIdx.x] = c;
    }
}

// Kernel 1 (fused): per-node class decode + sincos + cumsum rollout + vehicle
// masking + distance-loss block partials. One thread per node; pred reads are
// per-thread-contiguous (2880 B), every cache line fully consumed.
__global__ void __launch_bounds__(256) traj_kernel(const float* __restrict__ X,
                                                   const float* __restrict__ pred,
                                                   float2* __restrict__ traj,
                                                   float* __restrict__ distP,
                                                   unsigned* __restrict__ distC,
                                                   int n) {
    int i = blockIdx.x * 256 + threadIdx.x;
    float dsum = 0.0f;
    unsigned vehc = 0;
    if (i < n) {
        const float* xr = X + (size_t)i * 5;
        float typ = xr[0];
        float px = xr[1], py = xr[2];
        float tx = xr[3], ty = xr[4];
        bool veh = (typ == 0.0f);
        const float4* p = (const float4*)(pred + (size_t)i * (HORIZON * NCLASS));
        float4 outv[10];
        #pragma unroll
        for (int h = 0; h < HORIZON; h++) {
            float4 v[9];
            #pragma unroll
            for (int q = 0; q < 9; q++) v[q] = p[h * 9 + q];
            float best = -INFINITY; int bi = 0;
            #pragma unroll
            for (int q = 0; q < 9; q++) {
                float vals[4] = {v[q].x, v[q].y, v[q].z, v[q].w};
                #pragma unroll
                for (int k = 0; k < 4; k++) {
                    int c = q * 4 + k;
                    if (vals[k] > best) { best = vals[k]; bi = c; }  // strict > == first argmax
                }
            }
            float ang = (float)bi * TWO_PI_OVER_C * best;
            float s, c;
            sincosf(ang, &s, &c);
            px += STEP * c; py += STEP * s;
            float ox = veh ? px : 0.0f;
            float oy = veh ? py : 0.0f;
            if (h & 1) { outv[h >> 1].z = ox; outv[h >> 1].w = oy; }
            else       { outv[h >> 1].x = ox; outv[h >> 1].y = oy; }
            float dx = tx - ox, dy = ty - oy;
            dsum += veh ? sqrtf(fmaf(dy, dy, dx * dx)) : 0.0f;
        }
        float4* tp = (float4*)(traj + (size_t)i * HORIZON);
        #pragma unroll
        for (int q = 0; q < 10; q++) tp[q] = outv[q];
        vehc = veh ? 1u : 0u;
    }
    block_commit<256>(dsum, vehc, distP, distC);
}

// Kernel 2: obstacle edges. thr = X[src,3]+1 can be negative, so
// od < thr  <=>  (thr > 0) && (d2 < thr^2); 1/od = rsqrt(d2).
__global__ void __launch_bounds__(256) obstacle_kernel(const float* __restrict__ X,
                                                       const int* __restrict__ eo,
                                                       const float2* __restrict__ traj,
                                                       float* __restrict__ obsP,
                                                       unsigned* __restrict__ obsC,
                                                       int mo) {
    int e = blockIdx.x * 256 + threadIdx.x;
    float osum = 0.0f; unsigned ocnt = 0;
    if (e < mo) {
        int src = eo[e];
        int dst = eo[mo + e];
        const float* xr = X + (size_t)src * 5;
        float fx = xr[1], fy = xr[2];
        float thr = xr[3] + OBS_RADIUS;
        float thr2 = thr * thr;
        bool tpos = thr > 0.0f;
        const float4* tp = (const float4*)(traj + (size_t)dst * HORIZON);
        float4 buf[10];
        #pragma unroll
        for (int q = 0; q < 10; q++) buf[q] = tp[q];
        const float* f = (const float*)buf;
        #pragma unroll
        for (int h = 0; h < HORIZON; h++) {
            float dx = fx - f[2 * h], dy = fy - f[2 * h + 1];
            float d2 = fmaf(dy, dy, dx * dx);
            bool near = tpos && (d2 < thr2);
            ocnt += near ? 1u : 0u;
            osum += near ? rsqrtf(d2) : 0.0f;
        }
    }
    block_commit<256>(osum, ocnt, obsP, obsC);
}

// Kernel 3: vehicle edges, HxH all-pairs, 2 threads per edge (10 outer steps
// each) for more waves/CU. B-trajectory pinned in 40 VGPRs.
__global__ void __launch_bounds__(256) vehicle_kernel(const int* __restrict__ ev,
                                                      const float2* __restrict__ traj,
                                                      float* __restrict__ vehP,
                                                      unsigned* __restrict__ vehC,
                                                      int mv) {
    int t = blockIdx.x * 256 + threadIdx.x;
    int e = t >> 1;
    int half = t & 1;
    float vsum = 0.0f; unsigned vcnt = 0;
    if (e < mv) {
        int a = ev[e];
        int b = ev[mv + e];
        const float4* pb = (const float4*)(traj + (size_t)b * HORIZON);
        float4 tb[10];
        #pragma unroll
        for (int q = 0; q < 10; q++) tb[q] = pb[q];
        const float* fb = (const float*)tb;
        const float2* pa = traj + (size_t)a * HORIZON + half * 10;
        for (int i = 0; i < 10; i++) {
            float2 av = pa[i];
            #pragma unroll
            for (int j = 0; j < HORIZON; j++) {
                float dx = av.x - fb[2 * j];
                float dy = av.y - fb[2 * j + 1];
                float d2 = fmaf(dy, dy, dx * dx);
                bool near = d2 < 4.0f;       // vd < 2  <=>  d2 < 4
                vcnt += near ? 1u : 0u;
                vsum += near ? rsqrtf(d2) : 0.0f;  // 1/vd
            }
        }
    }
    block_commit<256>(vsum, vcnt, vehP, vehC);
}

// Kernel 4: reduce all block partials (double precision) -> 4 outputs.
__global__ void __launch_bounds__(256) finalize_kernel(
        const float* __restrict__ distP, const unsigned* __restrict__ distC, int nbR,
        const float* __restrict__ obsP,  const unsigned* __restrict__ obsC,  int nbO,
        const float* __restrict__ vehP,  const unsigned* __restrict__ vehC,  int nbV,
        float* __restrict__ out) {
    double s0 = 0, s1 = 0, s2 = 0;
    unsigned long long c0 = 0, c1 = 0, c2 = 0;
    for (int i = threadIdx.x; i < nbR; i += 256) { s0 += (double)distP[i]; c0 += distC[i]; }
    for (int i = threadIdx.x; i < nbO; i += 256) { s1 += (double)obsP[i];  c1 += obsC[i]; }
    for (int i = threadIdx.x; i < nbV; i += 256) { s2 += (double)vehP[i];  c2 += vehC[i]; }
    __shared__ double ds[3][4];
    __shared__ unsigned long long dc[3][4];
    double sv[3] = {s0, s1, s2};
    unsigned long long cv[3] = {c0, c1, c2};
    #pragma unroll
    for (int k = 0; k < 3; k++) {
        double v = sv[k]; unsigned long long cc = cv[k];
        #pragma unroll
        for (int off = 32; off > 0; off >>= 1) {
            v += __shfl_down(v, off, 64);
            cc += __shfl_down(cc, off, 64);
        }
        if ((threadIdx.x & 63) == 0) { ds[k][threadIdx.x >> 6] = v; dc[k][threadIdx.x >> 6] = cc; }
    }
    __syncthreads();
    if (threadIdx.x == 0) {
        double S[3]; unsigned long long C[3];
        #pragma unroll
        for (int k = 0; k < 3; k++) {
            S[k] = ds[k][0] + ds[k][1] + ds[k][2] + ds[k][3];
            C[k] = dc[k][0] + dc[k][1] + dc[k][2] + dc[k][3];
        }
        float dist = (C[0] > 0) ? (float)(S[0] / ((double)C[0] * (double)HORIZON)) : 0.0f;
        float obs  = (C[1] > 0) ? (float)(S[1] / (double)C[1]) : 0.0f;
        float veh  = (C[2] > 0) ? (float)(S[2] / (double)C[2]) : 0.0f;
        out[0] = dist + obs + veh;
        out[1] = dist;
        out[2] = obs;
        out[3] = veh;
    }
}

extern "C" void kernel_launch(void* const* d_in, const int* in_sizes, int n_in,
                              void* d_out, int out_size, void* d_ws, size_t ws_size,
                              hipStream_t stream) {
    const float* X    = (const float*)d_in[0];
    const float* pred = (const float*)d_in[1];
    const int*   ev   = (const int*)d_in[2];
    const int*   eo   = (const int*)d_in[3];
    int n_nodes = in_sizes[0] / 5;
    int mv = in_sizes[2] / 2;
    int mo = in_sizes[3] / 2;

    int nbR = (n_nodes + 255) / 256;
    int nbO = (mo + 255) / 256;
    int nbV = (2 * mv + 255) / 256;

    char* w = (char*)d_ws;
    float2* traj = (float2*)w;
    size_t off = (size_t)n_nodes * HORIZON * sizeof(float2);
    off = (off + 255) & ~(size_t)255;
    float*    distP = (float*)(w + off);    off += (size_t)nbR * 4;
    unsigned* distC = (unsigned*)(w + off); off += (size_t)nbR * 4;
    float*    obsP  = (float*)(w + off);    off += (size_t)nbO * 4;
    unsigned* obsC  = (unsigned*)(w + off); off += (size_t)nbO * 4;
    float*    vehP  = (float*)(w + off);    off += (size_t)nbV * 4;
    unsigned* vehC  = (unsigned*)(w + off); off += (size_t)nbV * 4;
    float* out = (float*)d_out;

    hipLaunchKernelGGL(traj_kernel, dim3(nbR), dim3(256), 0, stream,
                       X, pred, traj, distP, distC, n_nodes);
    hipLaunchKernelGGL(obstacle_kernel, dim3(nbO), dim3(256), 0, stream,
                       X, eo, traj, obsP, obsC, mo);
    hipLaunchKernelGGL(vehicle_kernel, dim3(nbV), dim3(256), 0, stream,
                       ev, traj, vehP, vehC, mv);
    hipLaunchKernelGGL(finalize_kernel, dim3(1), dim3(256), 0, stream,
                       distP, distC, nbR, obsP, obsC, nbO, vehP, vehC, nbV, out);
}

// Round 3
// 474.637 us; speedup vs baseline: 1.4651x; 1.0262x over previous
//
#include <hip/hip_runtime.h>
#include <math.h>

#define HORIZON 20
#define NCLASS  36
constexpr float STEP = 2.0f;
constexpr float TWO_PI_OVER_C = 0.17453292519943295f; // 2*pi/36
constexpr float OBS_RADIUS = 1.0f;
// VEH_RADIUS = 2.0 -> compare d^2 < 4.0

// Per-block (sum,count) reduction -> non-atomic partial store.
// ALL threads of the block must call this (no early returns before it).
template <int BS>
__device__ __forceinline__ void block_commit(float sum, unsigned cnt,
                                             float* __restrict__ pOut,
                                             unsigned* __restrict__ cOut) {
    __shared__ float    ls[BS / 64];
    __shared__ unsigned lc[BS / 64];
    #pragma unroll
    for (int off = 32; off > 0; off >>= 1) {
        sum += __shfl_down(sum, off, 64);
        cnt += __shfl_down(cnt, off, 64);
    }
    int wid = threadIdx.x >> 6;
    if ((threadIdx.x & 63) == 0) { ls[wid] = sum; lc[wid] = cnt; }
    __syncthreads();
    if (threadIdx.x == 0) {
        float s = 0.0f; unsigned c = 0u;
        #pragma unroll
        for (int w = 0; w < BS / 64; w++) { s += ls[w]; c += lc[w]; }
        pOut[blockIdx.x] = s;
        cOut[blockIdx.x] = c;
    }
}

// Kernel 1: class decode with FULLY COALESCED pred reads.
// Each wave handles 64 (node,h) rows = 2304 contiguous floats = 576 float4.
// Lane l loads float4 indices l, l+64, ..., l+512 (1 KB per wave instruction).
// Per-float4 (max, argcls) partials are exchanged via LDS; lane r then reduces
// row r's 9 partials in ascending class order (strict > == first argmax).
__global__ void __launch_bounds__(256) angles_kernel(const float* __restrict__ pred,
                                                     float2* __restrict__ steps,
                                                     int total_rows) {
    __shared__ float2 sm[4][576];   // [wave][row_local*9 + j]  (2-way bank alias: free)
    int wave = threadIdx.x >> 6;
    int lane = threadIdx.x & 63;
    int chunk = blockIdx.x * 4 + wave;
    int row0 = chunk * 64;
    int total_f4 = total_rows * 9;
    const float4* p4 = (const float4*)pred;
    #pragma unroll
    for (int q = 0; q < 9; q++) {
        int gl = q * 64 + lane;          // 0..575 position within the wave's chunk
        int g = row0 * 9 + gl;           // global float4 index
        float4 v;
        if (g < total_f4) v = p4[g];
        else v = make_float4(-INFINITY, -INFINITY, -INFINITY, -INFINITY);
        int j = gl % 9;                  // float4 position within its row (class base j*4)
        float m = v.x; int ii = 0;
        if (v.y > m) { m = v.y; ii = 1; }
        if (v.z > m) { m = v.z; ii = 2; }
        if (v.w > m) { m = v.w; ii = 3; }
        sm[wave][gl] = make_float2(m, (float)(j * 4 + ii));
    }
    __syncthreads();
    int row = row0 + lane;
    if (row < total_rows) {
        float best = -INFINITY; float bidx = 0.0f;
        #pragma unroll
        for (int j = 0; j < 9; j++) {
            float2 e = sm[wave][lane * 9 + j];
            if (e.x > best) { best = e.x; bidx = e.y; }   // ascending j: first-occurrence wins
        }
        float ang = bidx * TWO_PI_OVER_C * best;
        float s, c;
        sincosf(ang, &s, &c);
        steps[row] = make_float2(STEP * c, STEP * s);
    }
}

// Kernel 2: per-node cumsum rollout + vehicle masking + distance partials.
// steps[n*20..] is 160 B contiguous per thread (10 float4, 16B-aligned).
__global__ void __launch_bounds__(256) rollout_kernel(const float* __restrict__ X,
                                                      const float2* __restrict__ steps,
                                                      float2* __restrict__ traj,
                                                      float* __restrict__ distP,
                                                      unsigned* __restrict__ distC,
                                                      int n) {
    int i = blockIdx.x * 256 + threadIdx.x;
    float dsum = 0.0f;
    unsigned vehc = 0;
    if (i < n) {
        const float* xr = X + (size_t)i * 5;
        float typ = xr[0];
        float px = xr[1], py = xr[2];
        float tx = xr[3], ty = xr[4];
        bool veh = (typ == 0.0f);
        const float4* sp = (const float4*)(steps + (size_t)i * HORIZON);
        float4 buf[10];
        #pragma unroll
        for (int q = 0; q < 10; q++) buf[q] = sp[q];
        float* f = (float*)buf;
        #pragma unroll
        for (int h = 0; h < HORIZON; h++) {
            px += f[2 * h]; py += f[2 * h + 1];
            float ox = veh ? px : 0.0f;
            float oy = veh ? py : 0.0f;
            f[2 * h] = ox; f[2 * h + 1] = oy;
            float dx = tx - ox, dy = ty - oy;
            dsum += veh ? sqrtf(fmaf(dy, dy, dx * dx)) : 0.0f;
        }
        float4* tp = (float4*)(traj + (size_t)i * HORIZON);
        #pragma unroll
        for (int q = 0; q < 10; q++) tp[q] = buf[q];
        vehc = veh ? 1u : 0u;
    }
    block_commit<256>(dsum, vehc, distP, distC);
}

// Kernel 3: obstacle edges. thr = X[src,3]+1 can be negative, so
// od < thr  <=>  (thr > 0) && (d2 < thr^2); 1/od = rsqrt(d2).
__global__ void __launch_bounds__(256) obstacle_kernel(const float* __restrict__ X,
                                                       const int* __restrict__ eo,
                                                       const float2* __restrict__ traj,
                                                       float* __restrict__ obsP,
                                                       unsigned* __restrict__ obsC,
                                                       int mo) {
    int e = blockIdx.x * 256 + threadIdx.x;
    float osum = 0.0f; unsigned ocnt = 0;
    if (e < mo) {
        int src = eo[e];
        int dst = eo[mo + e];
        const float* xr = X + (size_t)src * 5;
        float fx = xr[1], fy = xr[2];
        float thr = xr[3] + OBS_RADIUS;
        float thr2 = thr * thr;
        bool tpos = thr > 0.0f;
        const float4* tp = (const float4*)(traj + (size_t)dst * HORIZON);
        float4 buf[10];
        #pragma unroll
        for (int q = 0; q < 10; q++) buf[q] = tp[q];
        const float* f = (const float*)buf;
        #pragma unroll
        for (int h = 0; h < HORIZON; h++) {
            float dx = fx - f[2 * h], dy = fy - f[2 * h + 1];
            float d2 = fmaf(dy, dy, dx * dx);
            bool near = tpos && (d2 < thr2);
            ocnt += near ? 1u : 0u;
            osum += near ? rsqrtf(d2) : 0.0f;
        }
    }
    block_commit<256>(osum, ocnt, obsP, obsC);
}

// Kernel 4: vehicle edges, HxH all-pairs, 2 threads per edge.
__global__ void __launch_bounds__(256) vehicle_kernel(const int* __restrict__ ev,
                                                      const float2* __restrict__ traj,
                                                      float* __restrict__ vehP,
                                                      unsigned* __restrict__ vehC,
                                                      int mv) {
    int t = blockIdx.x * 256 + threadIdx.x;
    int e = t >> 1;
    int half = t & 1;
    float vsum = 0.0f; unsigned vcnt = 0;
    if (e < mv) {
        int a = ev[e];
        int b = ev[mv + e];
        const float4* pb = (const float4*)(traj + (size_t)b * HORIZON);
        float4 tb[10];
        #pragma unroll
        for (int q = 0; q < 10; q++) tb[q] = pb[q];
        const float* fb = (const float*)tb;
        const float2* pa = traj + (size_t)a * HORIZON + half * 10;
        for (int i = 0; i < 10; i++) {
            float2 av = pa[i];
            #pragma unroll
            for (int j = 0; j < HORIZON; j++) {
                float dx = av.x - fb[2 * j];
                float dy = av.y - fb[2 * j + 1];
                float d2 = fmaf(dy, dy, dx * dx);
                bool near = d2 < 4.0f;             // vd < 2  <=>  d2 < 4
                vcnt += near ? 1u : 0u;
                vsum += near ? rsqrtf(d2) : 0.0f;  // 1/vd
            }
        }
    }
    block_commit<256>(vsum, vcnt, vehP, vehC);
}

// Kernel 5: reduce all block partials (double precision) -> 4 outputs.
__global__ void __launch_bounds__(256) finalize_kernel(
        const float* __restrict__ distP, const unsigned* __restrict__ distC, int nbR,
        const float* __restrict__ obsP,  const unsigned* __restrict__ obsC,  int nbO,
        const float* __restrict__ vehP,  const unsigned* __restrict__ vehC,  int nbV,
        float* __restrict__ out) {
    double s0 = 0, s1 = 0, s2 = 0;
    unsigned long long c0 = 0, c1 = 0, c2 = 0;
    for (int i = threadIdx.x; i < nbR; i += 256) { s0 += (double)distP[i]; c0 += distC[i]; }
    for (int i = threadIdx.x; i < nbO; i += 256) { s1 += (double)obsP[i];  c1 += obsC[i]; }
    for (int i = threadIdx.x; i < nbV; i += 256) { s2 += (double)vehP[i];  c2 += vehC[i]; }
    __shared__ double ds[3][4];
    __shared__ unsigned long long dc[3][4];
    double sv[3] = {s0, s1, s2};
    unsigned long long cv[3] = {c0, c1, c2};
    #pragma unroll
    for (int k = 0; k < 3; k++) {
        double v = sv[k]; unsigned long long cc = cv[k];
        #pragma unroll
        for (int off = 32; off > 0; off >>= 1) {
            v += __shfl_down(v, off, 64);
            cc += __shfl_down(cc, off, 64);
        }
        if ((threadIdx.x & 63) == 0) { ds[k][threadIdx.x >> 6] = v; dc[k][threadIdx.x >> 6] = cc; }
    }
    __syncthreads();
    if (threadIdx.x == 0) {
        double S[3]; unsigned long long C[3];
        #pragma unroll
        for (int k = 0; k < 3; k++) {
            S[k] = ds[k][0] + ds[k][1] + ds[k][2] + ds[k][3];
            C[k] = dc[k][0] + dc[k][1] + dc[k][2] + dc[k][3];
        }
        float dist = (C[0] > 0) ? (float)(S[0] / ((double)C[0] * (double)HORIZON)) : 0.0f;
        float obs  = (C[1] > 0) ? (float)(S[1] / (double)C[1]) : 0.0f;
        float veh  = (C[2] > 0) ? (float)(S[2] / (double)C[2]) : 0.0f;
        out[0] = dist + obs + veh;
        out[1] = dist;
        out[2] = obs;
        out[3] = veh;
    }
}

extern "C" void kernel_launch(void* const* d_in, const int* in_sizes, int n_in,
                              void* d_out, int out_size, void* d_ws, size_t ws_size,
                              hipStream_t stream) {
    const float* X    = (const float*)d_in[0];
    const float* pred = (const float*)d_in[1];
    const int*   ev   = (const int*)d_in[2];
    const int*   eo   = (const int*)d_in[3];
    int n_nodes = in_sizes[0] / 5;
    int mv = in_sizes[2] / 2;
    int mo = in_sizes[3] / 2;

    int total_rows = n_nodes * HORIZON;              // 2,000,000
    int nChunks = (total_rows + 63) / 64;            // 64 rows per wave
    int nbA = (nChunks + 3) / 4;                     // 4 waves per block
    int nbR = (n_nodes + 255) / 256;
    int nbO = (mo + 255) / 256;
    int nbV = (2 * mv + 255) / 256;

    char* w = (char*)d_ws;
    float2* steps = (float2*)w;
    size_t off = (size_t)total_rows * sizeof(float2);
    off = (off + 255) & ~(size_t)255;
    float2* traj = (float2*)(w + off);
    off += (size_t)total_rows * sizeof(float2);
    off = (off + 255) & ~(size_t)255;
    float*    distP = (float*)(w + off);    off += (size_t)nbR * 4;
    unsigned* distC = (unsigned*)(w + off); off += (size_t)nbR * 4;
    float*    obsP  = (float*)(w + off);    off += (size_t)nbO * 4;
    unsigned* obsC  = (unsigned*)(w + off); off += (size_t)nbO * 4;
    float*    vehP  = (float*)(w + off);    off += (size_t)nbV * 4;
    unsigned* vehC  = (unsigned*)(w + off); off += (size_t)nbV * 4;
    float* out = (float*)d_out;

    hipLaunchKernelGGL(angles_kernel, dim3(nbA), dim3(256), 0, stream,
                       pred, steps, total_rows);
    hipLaunchKernelGGL(rollout_kernel, dim3(nbR), dim3(256), 0, stream,
                       X, steps, traj, distP, distC, n_nodes);
    hipLaunchKernelGGL(obstacle_kernel, dim3(nbO), dim3(256), 0, stream,
                       X, eo, traj, obsP, obsC, mo);
    hipLaunchKernelGGL(vehicle_kernel, dim3(nbV), dim3(256), 0, stream,
                       ev, traj, vehP, vehC, mv);
    hipLaunchKernelGGL(finalize_kernel, dim3(1), dim3(256), 0, stream,
                       distP, distC, nbR, obsP, obsC, nbO, vehP, vehC, nbV, out);
}

// Round 4
// 452.852 us; speedup vs baseline: 1.5356x; 1.0481x over previous
//
#include <hip/hip_runtime.h>
#include <math.h>

#define HORIZON 20
#define NCLASS  36
constexpr float STEP = 2.0f;
constexpr float TWO_PI_OVER_C = 0.17453292519943295f; // 2*pi/36
constexpr float OBS_RADIUS = 1.0f;
// VEH_RADIUS = 2.0 -> compare d^2 < 4.0

// Per-block (sum,count) reduction -> non-atomic partial store.
// ALL threads of the block must call this (no early returns before it).
template <int BS>
__device__ __forceinline__ void block_commit(float sum, unsigned cnt,
                                             float* __restrict__ pOut,
                                             unsigned* __restrict__ cOut,
                                             int slot) {
    __shared__ float    ls[BS / 64];
    __shared__ unsigned lc[BS / 64];
    #pragma unroll
    for (int off = 32; off > 0; off >>= 1) {
        sum += __shfl_down(sum, off, 64);
        cnt += __shfl_down(cnt, off, 64);
    }
    int wid = threadIdx.x >> 6;
    if ((threadIdx.x & 63) == 0) { ls[wid] = sum; lc[wid] = cnt; }
    __syncthreads();
    if (threadIdx.x == 0) {
        float s = 0.0f; unsigned c = 0u;
        #pragma unroll
        for (int w = 0; w < BS / 64; w++) { s += ls[w]; c += lc[w]; }
        pOut[slot] = s;
        cOut[slot] = c;
    }
}

// Kernel 1: class decode with fully coalesced pred reads.
// Each wave handles 64 (node,h) rows = 2304 contiguous floats = 576 float4.
// Lane l loads float4 indices l, l+64, ..., l+512 (1 KB per wave instruction).
// Partials go through LDS as two float arrays (stride 9 floats, odd ->
// bank-conflict-free); lane r reduces row r's 9 partials in ascending class
// order (strict > == first argmax).
__global__ void __launch_bounds__(256) angles_kernel(const float* __restrict__ pred,
                                                     float2* __restrict__ steps,
                                                     int total_rows) {
    __shared__ float smM[4][576];
    __shared__ float smI[4][576];
    int wave = threadIdx.x >> 6;
    int lane = threadIdx.x & 63;
    int chunk = blockIdx.x * 4 + wave;
    int row0 = chunk * 64;
    int total_f4 = total_rows * 9;
    const float4* p4 = (const float4*)pred;
    #pragma unroll
    for (int q = 0; q < 9; q++) {
        int gl = q * 64 + lane;          // 0..575 position within the wave's chunk
        int g = row0 * 9 + gl;           // global float4 index
        float4 v;
        if (g < total_f4) v = p4[g];
        else v = make_float4(-INFINITY, -INFINITY, -INFINITY, -INFINITY);
        int j = gl % 9;                  // float4 position within its row (class base j*4)
        float m = v.x; int ii = 0;
        if (v.y > m) { m = v.y; ii = 1; }
        if (v.z > m) { m = v.z; ii = 2; }
        if (v.w > m) { m = v.w; ii = 3; }
        smM[wave][gl] = m;
        smI[wave][gl] = (float)(j * 4 + ii);
    }
    __syncthreads();
    int row = row0 + lane;
    if (row < total_rows) {
        float best = -INFINITY; float bidx = 0.0f;
        #pragma unroll
        for (int j = 0; j < 9; j++) {
            float m = smM[wave][lane * 9 + j];
            float id = smI[wave][lane * 9 + j];
            if (m > best) { best = m; bidx = id; }   // ascending j: first-occurrence wins
        }
        float ang = bidx * TWO_PI_OVER_C * best;
        float s, c;
        sincosf(ang, &s, &c);
        steps[row] = make_float2(STEP * c, STEP * s);
    }
}

// Kernel 2: per-node cumsum rollout + vehicle masking + distance partials.
// Also packs obstacle source info: obsInfo[n] = (x, y, thr^2 or -1, 0).
// (d2 < -1 is never true, so thr<=0 edges auto-reject and skip gathers.)
__global__ void __launch_bounds__(256) rollout_kernel(const float* __restrict__ X,
                                                      const float2* __restrict__ steps,
                                                      float2* __restrict__ traj,
                                                      float4* __restrict__ obsInfo,
                                                      float* __restrict__ distP,
                                                      unsigned* __restrict__ distC,
                                                      int n) {
    int i = blockIdx.x * 256 + threadIdx.x;
    float dsum = 0.0f;
    unsigned vehc = 0;
    if (i < n) {
        const float* xr = X + (size_t)i * 5;
        float typ = xr[0];
        float px = xr[1], py = xr[2];
        float tx = xr[3], ty = xr[4];
        float thr = tx + OBS_RADIUS;           // X[:,3] doubles as obstacle radius
        obsInfo[i] = make_float4(px, py, (thr > 0.0f) ? thr * thr : -1.0f, 0.0f);
        bool veh = (typ == 0.0f);
        const float4* sp = (const float4*)(steps + (size_t)i * HORIZON);
        float4 buf[10];
        #pragma unroll
        for (int q = 0; q < 10; q++) buf[q] = sp[q];
        float* f = (float*)buf;
        #pragma unroll
        for (int h = 0; h < HORIZON; h++) {
            px += f[2 * h]; py += f[2 * h + 1];
            float ox = veh ? px : 0.0f;
            float oy = veh ? py : 0.0f;
            f[2 * h] = ox; f[2 * h + 1] = oy;
            float dx = tx - ox, dy = ty - oy;
            dsum += veh ? sqrtf(fmaf(dy, dy, dx * dx)) : 0.0f;
        }
        float4* tp = (float4*)(traj + (size_t)i * HORIZON);
        #pragma unroll
        for (int q = 0; q < 10; q++) tp[q] = buf[q];
        vehc = veh ? 1u : 0u;
    }
    block_commit<256>(dsum, vehc, distP, distC, blockIdx.x);
}

// Kernel 3 (fused): obstacle edges on blocks [0, nbO), vehicle edges on
// blocks [nbO, nbO+nbV). Fusing overlaps the two sub-saturating phases.
__global__ void __launch_bounds__(256) edges_kernel(const float4* __restrict__ obsInfo,
                                                    const int* __restrict__ eo, int mo,
                                                    const int* __restrict__ ev, int mv,
                                                    const float2* __restrict__ traj,
                                                    float* __restrict__ obsP,
                                                    unsigned* __restrict__ obsC,
                                                    float* __restrict__ vehP,
                                                    unsigned* __restrict__ vehC,
                                                    int nbO) {
    if ((int)blockIdx.x < nbO) {
        // ---- obstacle path ----
        int e = blockIdx.x * 256 + threadIdx.x;
        float osum = 0.0f; unsigned ocnt = 0;
        if (e < mo) {
            int src = eo[e];
            int dst = eo[mo + e];
            float4 info = obsInfo[src];          // (x, y, thr2 or -1, 0)
            if (info.z >= 0.0f) {                // thr<=0 lanes skip the gather
                const float4* tp = (const float4*)(traj + (size_t)dst * HORIZON);
                float4 buf[10];
                #pragma unroll
                for (int q = 0; q < 10; q++) buf[q] = tp[q];
                const float* f = (const float*)buf;
                #pragma unroll
                for (int h = 0; h < HORIZON; h++) {
                    float dx = info.x - f[2 * h], dy = info.y - f[2 * h + 1];
                    float d2 = fmaf(dy, dy, dx * dx);
                    bool near = d2 < info.z;
                    ocnt += near ? 1u : 0u;
                    osum += near ? rsqrtf(d2) : 0.0f;
                }
            }
        }
        block_commit<256>(osum, ocnt, obsP, obsC, blockIdx.x);
    } else {
        // ---- vehicle path: 2 threads per edge, 10 outer steps each ----
        int t = (blockIdx.x - nbO) * 256 + threadIdx.x;
        int e = t >> 1;
        int half = t & 1;
        float vsum = 0.0f; unsigned vcnt = 0;
        if (e < mv) {
            int a = ev[e];
            int b = ev[mv + e];
            const float4* pb = (const float4*)(traj + (size_t)b * HORIZON);
            float4 tb[10];
            #pragma unroll
            for (int q = 0; q < 10; q++) tb[q] = pb[q];
            const float* fb = (const float*)tb;
            const float4* pa = (const float4*)(traj + (size_t)a * HORIZON + half * 10);
            float4 ta[5];
            #pragma unroll
            for (int q = 0; q < 5; q++) ta[q] = pa[q];
            const float* fa = (const float*)ta;
            #pragma unroll
            for (int i = 0; i < 10; i++) {
                float ax = fa[2 * i], ay = fa[2 * i + 1];
                #pragma unroll
                for (int j = 0; j < HORIZON; j++) {
                    float dx = ax - fb[2 * j];
                    float dy = ay - fb[2 * j + 1];
                    float d2 = fmaf(dy, dy, dx * dx);
                    bool near = d2 < 4.0f;             // vd < 2  <=>  d2 < 4
                    vcnt += near ? 1u : 0u;
                    vsum += near ? rsqrtf(d2) : 0.0f;  // 1/vd
                }
            }
        }
        block_commit<256>(vsum, vcnt, vehP, vehC, blockIdx.x - nbO);
    }
}

// Kernel 4: reduce all block partials (double precision) -> 4 outputs.
__global__ void __launch_bounds__(256) finalize_kernel(
        const float* __restrict__ distP, const unsigned* __restrict__ distC, int nbR,
        const float* __restrict__ obsP,  const unsigned* __restrict__ obsC,  int nbO,
        const float* __restrict__ vehP,  const unsigned* __restrict__ vehC,  int nbV,
        float* __restrict__ out) {
    double s0 = 0, s1 = 0, s2 = 0;
    unsigned long long c0 = 0, c1 = 0, c2 = 0;
    for (int i = threadIdx.x; i < nbR; i += 256) { s0 += (double)distP[i]; c0 += distC[i]; }
    for (int i = threadIdx.x; i < nbO; i += 256) { s1 += (double)obsP[i];  c1 += obsC[i]; }
    for (int i = threadIdx.x; i < nbV; i += 256) { s2 += (double)vehP[i];  c2 += vehC[i]; }
    __shared__ double ds[3][4];
    __shared__ unsigned long long dc[3][4];
    double sv[3] = {s0, s1, s2};
    unsigned long long cv[3] = {c0, c1, c2};
    #pragma unroll
    for (int k = 0; k < 3; k++) {
        double v = sv[k]; unsigned long long cc = cv[k];
        #pragma unroll
        for (int off = 32; off > 0; off >>= 1) {
            v += __shfl_down(v, off, 64);
            cc += __shfl_down(cc, off, 64);
        }
        if ((threadIdx.x & 63) == 0) { ds[k][threadIdx.x >> 6] = v; dc[k][threadIdx.x >> 6] = cc; }
    }
    __syncthreads();
    if (threadIdx.x == 0) {
        double S[3]; unsigned long long C[3];
        #pragma unroll
        for (int k = 0; k < 3; k++) {
            S[k] = ds[k][0] + ds[k][1] + ds[k][2] + ds[k][3];
            C[k] = dc[k][0] + dc[k][1] + dc[k][2] + dc[k][3];
        }
        float dist = (C[0] > 0) ? (float)(S[0] / ((double)C[0] * (double)HORIZON)) : 0.0f;
        float obs  = (C[1] > 0) ? (float)(S[1] / (double)C[1]) : 0.0f;
        float veh  = (C[2] > 0) ? (float)(S[2] / (double)C[2]) : 0.0f;
        out[0] = dist + obs + veh;
        out[1] = dist;
        out[2] = obs;
        out[3] = veh;
    }
}

extern "C" void kernel_launch(void* const* d_in, const int* in_sizes, int n_in,
                              void* d_out, int out_size, void* d_ws, size_t ws_size,
                              hipStream_t stream) {
    const float* X    = (const float*)d_in[0];
    const float* pred = (const float*)d_in[1];
    const int*   ev   = (const int*)d_in[2];
    const int*   eo   = (const int*)d_in[3];
    int n_nodes = in_sizes[0] / 5;
    int mv = in_sizes[2] / 2;
    int mo = in_sizes[3] / 2;

    int total_rows = n_nodes * HORIZON;              // 2,000,000
    int nChunks = (total_rows + 63) / 64;            // 64 rows per wave
    int nbA = (nChunks + 3) / 4;                     // 4 waves per block
    int nbR = (n_nodes + 255) / 256;
    int nbO = (mo + 255) / 256;
    int nbV = (2 * mv + 255) / 256;

    char* w = (char*)d_ws;
    float2* steps = (float2*)w;
    size_t off = (size_t)total_rows * sizeof(float2);
    off = (off + 255) & ~(size_t)255;
    float2* traj = (float2*)(w + off);
    off += (size_t)total_rows * sizeof(float2);
    off = (off + 255) & ~(size_t)255;
    float4* obsInfo = (float4*)(w + off);   off += (size_t)n_nodes * sizeof(float4);
    off = (off + 255) & ~(size_t)255;
    float*    distP = (float*)(w + off);    off += (size_t)nbR * 4;
    unsigned* distC = (unsigned*)(w + off); off += (size_t)nbR * 4;
    float*    obsP  = (float*)(w + off);    off += (size_t)nbO * 4;
    unsigned* obsC  = (unsigned*)(w + off); off += (size_t)nbO * 4;
    float*    vehP  = (float*)(w + off);    off += (size_t)nbV * 4;
    unsigned* vehC  = (unsigned*)(w + off); off += (size_t)nbV * 4;
    float* out = (float*)d_out;

    hipLaunchKernelGGL(angles_kernel, dim3(nbA), dim3(256), 0, stream,
                       pred, steps, total_rows);
    hipLaunchKernelGGL(rollout_kernel, dim3(nbR), dim3(256), 0, stream,
                       X, steps, traj, obsInfo, distP, distC, n_nodes);
    hipLaunchKernelGGL(edges_kernel, dim3(nbO + nbV), dim3(256), 0, stream,
                       obsInfo, eo, mo, ev, mv, traj, obsP, obsC, vehP, vehC, nbO);
    hipLaunchKernelGGL(finalize_kernel, dim3(1), dim3(256), 0, stream,
                       distP, distC, nbR, obsP, obsC, nbO, vehP, vehC, nbV, out);
}